// Round 13
// baseline (451.357 us; speedup 1.0000x reference)
//
#include <hip/hip_runtime.h>
#include <hip/hip_bf16.h>

#define BB 16
#define LL 256
#define DD 256
#define DI 512
#define DS 16

typedef __attribute__((ext_vector_type(8))) short bf16x8;
typedef __attribute__((ext_vector_type(4))) short bf16x4;
typedef __attribute__((ext_vector_type(4))) float f32x4;
typedef __attribute__((ext_vector_type(2))) float fx2;

__device__ inline short f2bf(float f) {
    __hip_bfloat16 h = __float2bfloat16(f);
    return *reinterpret_cast<short*>(&h);
}
__device__ inline float bf2f_s(short s) {
    __hip_bfloat16 h = *reinterpret_cast<__hip_bfloat16*>(&s);
    return __bfloat162float(h);
}
__device__ inline void stf(float* p, float v) { *p = v; }
__device__ inline void stf(__hip_bfloat16* p, float v) { *p = __float2bfloat16(v); }

// packed fp32 (CDNA2+ full-rate dual-f32, VOP3P) — hipcc won't auto-form these
__device__ inline fx2 pk_fma(fx2 a, fx2 b, fx2 c) {
    fx2 d;
    asm("v_pk_fma_f32 %0, %1, %2, %3" : "=v"(d) : "v"(a), "v"(b), "v"(c));
    return d;
}
__device__ inline fx2 pk_mul(fx2 a, fx2 b) {
    fx2 d;
    asm("v_pk_mul_f32 %0, %1, %2" : "=v"(d) : "v"(a), "v"(b));
    return d;
}
__device__ inline fx2 pk_add(fx2 a, fx2 b) {
    fx2 d;
    asm("v_pk_add_f32 %0, %1, %2" : "=v"(d) : "v"(a), "v"(b));
    return d;
}

// unpack 16 contiguous bf16 from LDS into 16 floats
__device__ inline void unpack16(const short* p, float* f) {
    bf16x8 v0 = *(const bf16x8*)p;
    bf16x8 v1 = *(const bf16x8*)(p + 8);
    const unsigned* a = (const unsigned*)&v0;
    const unsigned* b = (const unsigned*)&v1;
#pragma unroll
    for (int j = 0; j < 4; ++j) {
        f[2 * j]     = __uint_as_float(a[j] << 16);
        f[2 * j + 1] = __uint_as_float(a[j] & 0xFFFF0000u);
        f[8 + 2 * j]     = __uint_as_float(b[j] << 16);
        f[8 + 2 * j + 1] = __uint_as_float(b[j] & 0xFFFF0000u);
    }
}
// unpack 16 contiguous bf16 from LDS into 8 f32 pairs
__device__ inline void unpack16p(const short* p, fx2* f) {
    bf16x8 v0 = *(const bf16x8*)p;
    bf16x8 v1 = *(const bf16x8*)(p + 8);
    const unsigned* a = (const unsigned*)&v0;
    const unsigned* b = (const unsigned*)&v1;
#pragma unroll
    for (int j = 0; j < 4; ++j) {
        f[j] = (fx2){__uint_as_float(a[j] << 16), __uint_as_float(a[j] & 0xFFFF0000u)};
        f[4 + j] = (fx2){__uint_as_float(b[j] << 16), __uint_as_float(b[j] & 0xFFFF0000u)};
    }
}
// load 16 f32 from LDS
__device__ inline void load16f(const float* p, float* f) {
    const f32x4* cp = (const f32x4*)p;
    f32x4 c0 = cp[0], c1 = cp[1], c2 = cp[2], c3 = cp[3];
    f[0]=c0[0]; f[1]=c0[1]; f[2]=c0[2]; f[3]=c0[3];
    f[4]=c1[0]; f[5]=c1[1]; f[6]=c1[2]; f[7]=c1[3];
    f[8]=c2[0]; f[9]=c2[1]; f[10]=c2[2]; f[11]=c2[3];
    f[12]=c3[0]; f[13]=c3[1]; f[14]=c3[2]; f[15]=c3[3];
}

// ---------------- weight fp32->bf16 pre-convert (once per call) ----------------
__global__ __launch_bounds__(256) void cvt_w(
    const float* __restrict__ s0, const float* __restrict__ s1,
    const float* __restrict__ s2, const float* __restrict__ s3,
    const float* __restrict__ s4, const float* __restrict__ s5,
    __hip_bfloat16* __restrict__ dst) {
    int i = blockIdx.x * 256 + threadIdx.x;      // vec4 index
    if (i >= 491520) return;
    int e = i * 4;
    const float* src; int off;
    if (e < 1048576)      { src = s0; off = e; }
    else if (e < 1179648) { src = s1; off = e - 1048576; }
    else if (e < 1310720) { src = s2; off = e - 1179648; }
    else if (e < 1376256) { src = s3; off = e - 1310720; }
    else if (e < 1441792) { src = s4; off = e - 1376256; }
    else                  { src = s5; off = e - 1441792; }
    float4 v = *(const float4*)(src + off);
    bf16x4 r;
    r[0] = f2bf(v.x); r[1] = f2bf(v.y); r[2] = f2bf(v.z); r[3] = f2bf(v.w);
    *(bf16x4*)((short*)dst + e) = r;
}

// ---------------- patch embed ----------------
__global__ __launch_bounds__(256) void patch_embed(const float* __restrict__ x,
                                                   const float* __restrict__ pw,
                                                   const float* __restrict__ pb,
                                                   float* __restrict__ h) {
    int blk = blockIdx.x;           // b*16 + lg
    int b = blk >> 4, lg = blk & 15;
    int tid = threadIdx.x;
    __shared__ float pws[48 * 258];
    __shared__ float xs[16][48];
    for (int it = 0; it < 48; ++it) {
        int idx = tid + it * 256;
        float v = pw[idx];
        int dd = idx / 48, k = idx - dd * 48;
        pws[k * 258 + dd] = v;
    }
    for (int idx = tid; idx < 16 * 48; idx += 256) {
        int li = idx / 48, k = idx - li * 48;
        int c = k >> 4, py = (k >> 2) & 3, px = k & 3;
        xs[li][k] = x[(size_t)(b * 3 + c) * 4096 + (lg * 4 + py) * 64 + li * 4 + px];
    }
    __syncthreads();
    float bv = pb[tid];
#pragma unroll 4
    for (int li = 0; li < 16; ++li) {
        float acc = bv;
#pragma unroll
        for (int k = 0; k < 48; ++k) acc += xs[li][k] * pws[k * 258 + tid];
        h[((size_t)(b * 256 + lg * 16 + li)) * 256 + tid] = acc;
    }
}

// ---------------- time embedding ----------------
__global__ void time_embed(const int* __restrict__ t, const float* __restrict__ tw1,
                           const float* __restrict__ tb1, const float* __restrict__ tw2,
                           const float* __restrict__ tb2, float* __restrict__ te) {
    int b = blockIdx.x, j = threadIdx.x;
    __shared__ float s0[256], s1[256];
    float tv = (float)t[b];
    if (j < 128) {
        float f = expf((float)j * (-9.210340371976184f / 127.f));
        float a = tv * f;
        s0[j] = sinf(a);
        s0[j + 128] = cosf(a);
    }
    __syncthreads();
    float acc = tb1[j];
    for (int k = 0; k < 256; ++k) acc += s0[k] * tw1[j * 256 + k];
    s1[j] = acc / (1.f + expf(-acc));
    __syncthreads();
    float acc2 = tb2[j];
    for (int k = 0; k < 256; ++k) acc2 += s1[k] * tw2[j * 256 + k];
    te[b * 256 + j] = acc2;
}

// ---------------- layernorm (per-layer, +te) ----------------
template <typename TO>
__global__ void ln_kernel(const float* __restrict__ h, const float* __restrict__ te,
                          const float* __restrict__ g, const float* __restrict__ bta,
                          TO* __restrict__ out) {
    int row = blockIdx.x;
    int b = row >> 8;
    int d = threadIdx.x;
    float v = h[(size_t)row * 256 + d] + (te ? te[b * 256 + d] : 0.f);
    float s = v, s2 = v * v;
#pragma unroll
    for (int o = 32; o; o >>= 1) {
        s += __shfl_down(s, o, 64);
        s2 += __shfl_down(s2, o, 64);
    }
    __shared__ float ws[4], ws2[4];
    int wid = threadIdx.x >> 6, lane = threadIdx.x & 63;
    if (lane == 0) { ws[wid] = s; ws2[wid] = s2; }
    __syncthreads();
    float mu = (ws[0] + ws[1] + ws[2] + ws[3]) * (1.f / 256.f);
    float m2 = (ws2[0] + ws2[1] + ws2[2] + ws2[3]) * (1.f / 256.f);
    float var = m2 - mu * mu;
    stf(&out[(size_t)row * 256 + d], (v - mu) * rsqrtf(var + 1e-5f) * g[d] + bta[d]);
}

// ---------------- bf16 MFMA GEMM (bf16 weights) ----------------
template <int BM, int BN, int WM, int WN, int FM, int FN, int ACT, bool ADD,
          bool HASBIAS, int AMODE, bool OBF>
__global__ __launch_bounds__(256) void gemm_mfma(
    const void* __restrict__ Ap, const __hip_bfloat16* __restrict__ W,
    const float* __restrict__ bias, void* __restrict__ Cp,
    int M, int N, int K, int lda,
    const void* __restrict__ A2p, const __hip_bfloat16* __restrict__ W2,
    const float* __restrict__ bias2, int nsplit)
{
    constexpr int LDP = 40;
    __shared__ __align__(16) short As[BM * LDP];
    __shared__ __align__(16) short Ws[BN * LDP];
    int tid = threadIdx.x;
    int lane = tid & 63;
    int w = tid >> 6;
    int wm, wn;
    if (WN == 1) { wm = w; wn = 0; } else { wm = w >> 1; wn = w & 1; }
    int m0 = blockIdx.x * BM;
    int n0 = blockIdx.y * BN;
    int wn0 = n0;
    if (nsplit > 0 && n0 >= nsplit) { Ap = A2p; W = W2; bias = bias2; wn0 = n0 - nsplit; }

    f32x4 acc[FM][FN];
#pragma unroll
    for (int i = 0; i < FM; ++i)
#pragma unroll
        for (int j = 0; j < FN; ++j) acc[i][j] = (f32x4){0.f, 0.f, 0.f, 0.f};

    for (int k0 = 0; k0 < K; k0 += 32) {
        if (AMODE == 0) {
            for (int idx = tid; idx < BM * 4; idx += 256) {
                int row = idx >> 2, qc = idx & 3;
                const __hip_bfloat16* g = (const __hip_bfloat16*)Ap +
                    (size_t)(m0 + row) * lda + k0 + qc * 8;
                *(bf16x8*)&As[row * LDP + qc * 8] = *(const bf16x8*)g;
            }
        } else if (AMODE == 1) {
            for (int idx = tid; idx < BM * 4; idx += 256) {
                int row = idx >> 2, qc = idx & 3;
                const float* g = (const float*)Ap + (size_t)(m0 + row) * lda + k0 + qc * 8;
                float4 v0 = *(const float4*)g;
                float4 v1 = *(const float4*)(g + 4);
                union { bf16x8 v; short s[8]; } u8;
                u8.s[0] = f2bf(v0.x); u8.s[1] = f2bf(v0.y); u8.s[2] = f2bf(v0.z); u8.s[3] = f2bf(v0.w);
                u8.s[4] = f2bf(v1.x); u8.s[5] = f2bf(v1.y); u8.s[6] = f2bf(v1.z); u8.s[7] = f2bf(v1.w);
                *(bf16x8*)&As[row * LDP + qc * 8] = u8.v;
            }
        } else {
            for (int idx = tid; idx < BM * 4; idx += 256) {
                int row = idx >> 2, qc = idx & 3;
                size_t rb = (size_t)(m0 + row) * 1024 + k0 + qc * 8;
                union { bf16x8 v; short s[8]; } uf, ub, uz, r;
                uf.v = *(const bf16x8*)((const __hip_bfloat16*)Ap + rb);
                ub.v = *(const bf16x8*)((const __hip_bfloat16*)Ap + rb + 512);
                uz.v = *(const bf16x8*)((const __hip_bfloat16*)A2p + rb + 512);
#pragma unroll
                for (int e = 0; e < 8; ++e) {
                    float z = bf2f_s(uz.s[e]);
                    float sg = z / (1.f + __expf(-z));
                    r.s[e] = f2bf((bf2f_s(uf.s[e]) + bf2f_s(ub.s[e])) * sg);
                }
                *(bf16x8*)&As[row * LDP + qc * 8] = r.v;
            }
        }
        for (int idx = tid; idx < BN * 4; idx += 256) {
            int row = idx >> 2, qc = idx & 3;
            const __hip_bfloat16* g = W + (size_t)(wn0 + row) * K + k0 + qc * 8;
            *(bf16x8*)&Ws[row * LDP + qc * 8] = *(const bf16x8*)g;
        }
        __syncthreads();
        int kg = lane >> 4, r = lane & 15;
        bf16x8 af[FM], bfr[FN];
#pragma unroll
        for (int i = 0; i < FM; ++i)
            af[i] = *(const bf16x8*)&As[(wm * FM * 16 + i * 16 + r) * LDP + kg * 8];
#pragma unroll
        for (int j = 0; j < FN; ++j)
            bfr[j] = *(const bf16x8*)&Ws[(wn * FN * 16 + j * 16 + r) * LDP + kg * 8];
#pragma unroll
        for (int i = 0; i < FM; ++i)
#pragma unroll
            for (int j = 0; j < FN; ++j)
                acc[i][j] = __builtin_amdgcn_mfma_f32_16x16x32_bf16(af[i], bfr[j], acc[i][j], 0, 0, 0);
        __syncthreads();
    }
    int r = lane & 15, qg = lane >> 4;
#pragma unroll
    for (int i = 0; i < FM; ++i) {
#pragma unroll
        for (int j = 0; j < FN; ++j) {
            int col = n0 + wn * FN * 16 + j * 16 + r;
            int colw = wn0 + wn * FN * 16 + j * 16 + r;
            float bv = HASBIAS ? bias[colw] : 0.f;
#pragma unroll
            for (int q = 0; q < 4; ++q) {
                int rowm = m0 + wm * FM * 16 + i * 16 + qg * 4 + q;
                float v = acc[i][j][q] + bv;
                if (ACT == 1) v = (v > 20.f) ? v : log1pf(__expf(v));
                size_t o = (size_t)rowm * N + col;
                if (OBF) ((__hip_bfloat16*)Cp)[o] = __float2bfloat16(v);
                else if (ADD) ((float*)Cp)[o] += v;
                else ((float*)Cp)[o] = v;
            }
        }
    }
}

// ---------------- head: fused final-LN + GEMM + unpatchify ----------------
__global__ __launch_bounds__(256) void head_fused(
    const float* __restrict__ A, const float* __restrict__ fng,
    const float* __restrict__ fnb, const float* __restrict__ W,
    const float* __restrict__ bias, float* __restrict__ C) {
    __shared__ float Asm[16][65];
    __shared__ float Wsm[16][65];
    __shared__ float mu_s[64], rs_s[64];
    __shared__ float red[256], red2[256];
    int tid = threadIdx.x;
    int m0 = blockIdx.x * 64;
    {
        int rr = tid >> 2, part = tid & 3;
        const float* hrow = A + (size_t)(m0 + rr) * 256 + part * 64;
        float s = 0.f, s2 = 0.f;
#pragma unroll
        for (int j = 0; j < 16; ++j) {
            float4 v = *(const float4*)(hrow + j * 4);
            s += v.x + v.y + v.z + v.w;
            s2 += v.x * v.x + v.y * v.y + v.z * v.z + v.w * v.w;
        }
        red[tid] = s; red2[tid] = s2;
    }
    __syncthreads();
    if ((tid & 3) == 0) {
        int rr = tid >> 2;
        float S = red[tid] + red[tid + 1] + red[tid + 2] + red[tid + 3];
        float S2 = red2[tid] + red2[tid + 1] + red2[tid + 2] + red2[tid + 3];
        float mu = S * (1.f / 256.f);
        float var = S2 * (1.f / 256.f) - mu * mu;
        mu_s[rr] = mu;
        rs_s[rr] = rsqrtf(var + 1e-5f);
    }
    __syncthreads();
    int tx = tid & 15, ty = tid >> 4;
    float acc[4][4] = {};
    for (int k0 = 0; k0 < 256; k0 += 16) {
#pragma unroll
        for (int i = 0; i < 4; ++i) {
            int idx = tid + i * 256;
            int rr = idx >> 4, cc = idx & 15;
            float v = A[(size_t)(m0 + rr) * 256 + k0 + cc];
            Asm[cc][rr] = (v - mu_s[rr]) * rs_s[rr] * fng[k0 + cc] + fnb[k0 + cc];
            Wsm[cc][rr] = (rr < 48) ? W[(size_t)rr * 256 + k0 + cc] : 0.f;
        }
        __syncthreads();
#pragma unroll
        for (int k = 0; k < 16; ++k) {
            float av[4], wv[4];
#pragma unroll
            for (int i = 0; i < 4; ++i) av[i] = Asm[k][ty * 4 + i];
#pragma unroll
            for (int j = 0; j < 4; ++j) wv[j] = Wsm[k][tx * 4 + j];
#pragma unroll
            for (int i = 0; i < 4; ++i)
#pragma unroll
                for (int j = 0; j < 4; ++j) acc[i][j] += av[i] * wv[j];
        }
        __syncthreads();
    }
#pragma unroll
    for (int i = 0; i < 4; ++i) {
        int m = m0 + ty * 4 + i;
#pragma unroll
        for (int j = 0; j < 4; ++j) {
            int n = tx * 4 + j;
            if (n < 48) {
                float v = acc[i][j] + bias[n];
                int b = m >> 8, l = m & 255;
                int c = n >> 4;
                int hy = ((l >> 4) << 2) + ((n >> 2) & 3);
                int wx = ((l & 15) << 2) + (n & 3);
                C[(size_t)(b * 3 + c) * 4096 + hy * 64 + wx] = v;
            }
        }
    }
}

// ---------------- causal depthwise conv (k=4) + silu ----------------
__global__ __launch_bounds__(256) void conv_silu(
    const __hip_bfloat16* __restrict__ xz, const float* __restrict__ cw,
    const float* __restrict__ cb, __hip_bfloat16* __restrict__ u) {
    int g = blockIdx.x * 4 + (threadIdx.x >> 6);
    int lane = threadIdx.x & 63;
    int l = g & 255;
    int d0 = lane * 8;
    const __hip_bfloat16* base = xz + (size_t)g * 1024 + d0;
    union { bf16x8 v; short s[8]; } t0, t1, t2, t3, r;
    bf16x8 zz = {};
    t3.v = *(const bf16x8*)base;
    t2.v = (l >= 1) ? *(const bf16x8*)(base - 1024) : zz;
    t1.v = (l >= 2) ? *(const bf16x8*)(base - 2048) : zz;
    t0.v = (l >= 3) ? *(const bf16x8*)(base - 3072) : zz;
#pragma unroll
    for (int e = 0; e < 8; ++e) {
        int d = d0 + e;
        const float4 wv = *(const float4*)(cw + d * 4);
        float acc = cb[d] + bf2f_s(t0.s[e]) * wv.x + bf2f_s(t1.s[e]) * wv.y +
                    bf2f_s(t2.s[e]) * wv.z + bf2f_s(t3.s[e]) * wv.w;
        r.s[e] = f2bf(acc / (1.f + __expf(-acc)));
    }
    *(bf16x8*)(u + (size_t)g * 512 + d0) = r.v;
}

// ================= fused SSM scan v11: packed-f32 pass A =================
// 512 blocks (XCD-swizzled), 512 threads = 16 chunks x 32 channels.
// Pass A inner loop uses v_pk_fma_f32/v_pk_mul_f32 (2 f32 per issue slot).
__global__ __launch_bounds__(512) void scan_fused(
    const __hip_bfloat16* __restrict__ u, const float* __restrict__ pf2,
    const __hip_bfloat16* __restrict__ dtwF, const __hip_bfloat16* __restrict__ dtwB,
    const float* __restrict__ dtbF, const float* __restrict__ dtbB,
    const float* __restrict__ Alog_f, const float* __restrict__ Alog_b,
    const float* __restrict__ Dv_f, const float* __restrict__ Dv_b,
    __hip_bfloat16* __restrict__ y2)
{
    int blk = blockIdx.x;
    int c8 = blk & 7, idxb = blk >> 3;
    int bd = c8 + 8 * (idxb & 3);      // XCD swizzle
    int dg = idxb >> 2;
    int dir = bd & 1, b = bd >> 1;
    int tid = threadIdx.x;
    int dl = tid & 31, cc = tid >> 5;
    int d0 = dg * 32;
    int d = d0 + dl;
    int poff = dir ? 64 : 0;
    int doff = dir ? 512 : 0;
    const float* Alog = dir ? Alog_b : Alog_f;
    float Dval = (dir ? Dv_b : Dv_f)[d];
    const __hip_bfloat16* dtw = dir ? dtwB : dtwF;
    const float* dtb = dir ? dtbB : dtbF;

    constexpr int DTL = 33;
    __shared__ __align__(16) short DTs[256 * DTL];   // 16.5 KB
    __shared__ __align__(16) short Bsm[256 * 16];    // 8 KB  bf16 (scan order)
    __shared__ __align__(16) float Csm[256 * 16];    // 16 KB f32  (scan order)
    __shared__ __align__(16) unsigned PFR[8192];     // 32 KB: dtp+dtw staging, then P|F
    short* dtpL = (short*)PFR;                       // 20480 B
    short* dtwL = (short*)PFR + 10240;               // 2560 B

    int i0 = cc * 16;
    int row0 = b * 256 + (dir ? 255 - i0 : i0);
    int stpE = dir ? -1 : 1;
    int dstep = stpE * 1024, ustep = stpE * 512;
    const __hip_bfloat16* up0 = u + (size_t)row0 * 512 + d;
    __hip_bfloat16* yp0 = y2 + (size_t)row0 * 1024 + doff + d;

    float ureg[16];
#pragma unroll
    for (int k = 0; k < 16; ++k) ureg[k] = __bfloat162float(up0[k * ustep]);

    // ---- staging ----
    for (int idx = tid; idx < 1024; idx += 512) {    // C f32
        int i = idx >> 2, q = idx & 3;
        int tt = dir ? 255 - i : i;
        *(f32x4*)&Csm[i * 16 + q * 4] =
            *(const f32x4*)(pf2 + ((size_t)b * 256 + tt) * 128 + poff + 48 + q * 4);
    }
    {                                                // B bf16
        int idx = tid;
        int i = idx >> 1, half = idx & 1;
        int tt = dir ? 255 - i : i;
        const float* pr = pf2 + ((size_t)b * 256 + tt) * 128 + poff + 32 + half * 8;
        float4 v0 = *(const float4*)pr;
        float4 v1 = *(const float4*)(pr + 4);
        union { bf16x8 v; short s[8]; } u8;
        u8.s[0] = f2bf(v0.x); u8.s[1] = f2bf(v0.y); u8.s[2] = f2bf(v0.z); u8.s[3] = f2bf(v0.w);
        u8.s[4] = f2bf(v1.x); u8.s[5] = f2bf(v1.y); u8.s[6] = f2bf(v1.z); u8.s[7] = f2bf(v1.w);
        *(bf16x8*)&Bsm[i * 16 + half * 8] = u8.v;
    }
    for (int idx = tid; idx < 2048; idx += 512) {    // dtp (raw row order)
        int row = idx >> 3, q = idx & 7;
        float4 v = *(const float4*)(pf2 + ((size_t)(b * 256 + row)) * 128 + poff + q * 4);
        bf16x4 r4; r4[0] = f2bf(v.x); r4[1] = f2bf(v.y); r4[2] = f2bf(v.z); r4[3] = f2bf(v.w);
        *(bf16x4*)&dtpL[row * 40 + q * 4] = r4;
    }
    if (tid < 128) {                                 // dtw rows d0..d0+31
        int row = tid >> 2, q = tid & 3;
        *(bf16x8*)&dtwL[row * 40 + q * 8] =
            *(const bf16x8*)(dtw + (size_t)(d0 + row) * 32 + q * 8);
    }
    // ---- A-structure check ----
    float A0c;
    int okl = 1;
    {
        const float* ap = Alog + d * 16;
        float A0 = -__expf(ap[0]);
        A0c = A0 * 1.44269504f;
#pragma unroll
        for (int s = 1; s < 16; ++s) {
            float As_ = -__expf(ap[s]);
            okl = okl && (fabsf(As_ - (float)(s + 1) * A0) <= 1e-3f * (float)(s + 1));
        }
    }
    bool fast = __syncthreads_and(okl) != 0;   // barrier #1

    // ---- dt via MFMA ----
    {
        int w = tid >> 6, lane = tid & 63;
        int r = lane & 15, kg = lane >> 4;
#pragma unroll
        for (int p = 0; p < 4; ++p) {
            int t = 2 * w + (p >> 1);
            int ct = p & 1;
            bf16x8 af = *(const bf16x8*)&dtpL[(t * 16 + r) * 40 + kg * 8];
            bf16x8 bfr = *(const bf16x8*)&dtwL[(ct * 16 + r) * 40 + kg * 8];
            f32x4 acc = (f32x4){0.f, 0.f, 0.f, 0.f};
            acc = __builtin_amdgcn_mfma_f32_16x16x32_bf16(af, bfr, acc, 0, 0, 0);
            int colL = ct * 16 + r;
            float bvv = dtb[d0 + colL];
#pragma unroll
            for (int q = 0; q < 4; ++q) {
                int rowl = t * 16 + kg * 4 + q;
                float vdt = acc[q] + bvv;
                vdt = (vdt > 20.f) ? vdt : log1pf(__expf(vdt));
                DTs[rowl * DTL + colL] = f2bf(vdt);
            }
        }
    }
    __syncthreads();   // barrier #2

    if (fast) {
        fx2 hp[8];
#pragma unroll
        for (int j = 0; j < 8; ++j) hp[j] = (fx2){0.f, 0.f};
        float yl[16];
        float S = 0.f;
        // ---- Pass A: packed-f32 inner loop ----
#pragma unroll
        for (int k = 0; k < 16; ++k) {
            int i = i0 + k;
            int tt = dir ? 255 - i : i;
            float dt_ = bf2f_s(DTs[tt * DTL + dl]);
            S += dt_;
            float du = dt_ * ureg[k];
            fx2 Bp[8];
            unpack16p(&Bsm[i * 16], Bp);
            const fx2* Cp = (const fx2*)&Csm[i * 16];
            float p1 = exp2f(dt_ * A0c);
            float p2 = p1 * p1;
            fx2 p2p = {p2, p2};
            fx2 dud = {du, du};
            fx2 pp = {p1, p2};
            fx2 ys0, ys1, ys2, ys3;
            hp[0] = pk_fma(pp, hp[0], pk_mul(dud, Bp[0])); ys0 = pk_mul(Cp[0], hp[0]);
            pp = pk_mul(pp, p2p);
            hp[1] = pk_fma(pp, hp[1], pk_mul(dud, Bp[1])); ys1 = pk_mul(Cp[1], hp[1]);
            pp = pk_mul(pp, p2p);
            hp[2] = pk_fma(pp, hp[2], pk_mul(dud, Bp[2])); ys2 = pk_mul(Cp[2], hp[2]);
            pp = pk_mul(pp, p2p);
            hp[3] = pk_fma(pp, hp[3], pk_mul(dud, Bp[3])); ys3 = pk_mul(Cp[3], hp[3]);
            pp = pk_mul(pp, p2p);
            hp[4] = pk_fma(pp, hp[4], pk_mul(dud, Bp[4])); ys0 = pk_fma(Cp[4], hp[4], ys0);
            pp = pk_mul(pp, p2p);
            hp[5] = pk_fma(pp, hp[5], pk_mul(dud, Bp[5])); ys1 = pk_fma(Cp[5], hp[5], ys1);
            pp = pk_mul(pp, p2p);
            hp[6] = pk_fma(pp, hp[6], pk_mul(dud, Bp[6])); ys2 = pk_fma(Cp[6], hp[6], ys2);
            pp = pk_mul(pp, p2p);
            hp[7] = pk_fma(pp, hp[7], pk_mul(dud, Bp[7])); ys3 = pk_fma(Cp[7], hp[7], ys3);
            fx2 t01 = pk_add(ys0, ys1);
            fx2 t23 = pk_add(ys2, ys3);
            fx2 tt2 = pk_add(t01, t23);
            yl[k] = fmaf(ureg[k], Dval, tt2[0] + tt2[1]);
        }
        // chunk decay W^(s+1), tree
        {
            float W1 = exp2f(S * A0c);
            float W2 = W1 * W1, W3 = W2 * W1, W4 = W2 * W2;
            float W5 = W4 * W1, W6 = W4 * W2, W7 = W4 * W3, W8 = W4 * W4;
            float Pv[16] = {W1, W2, W3, W4, W5, W6, W7, W8,
                            W8 * W1, W8 * W2, W8 * W3, W8 * W4,
                            W8 * W5, W8 * W6, W8 * W7, W8 * W8};
            const float* hs = (const float*)hp;
#pragma unroll
            for (int s = 0; s < 16; ++s) {
                unsigned wrd = (unsigned)(unsigned short)f2bf(Pv[s]) |
                               ((unsigned)(unsigned short)f2bf(hs[s]) << 16);
                PFR[(s * 16 + cc) * 32 + dl] = wrd;
            }
        }
        __syncthreads();   // barrier #3
        {
            int s2 = tid >> 5, dl2 = tid & 31;
            float hh = 0.f;
#pragma unroll
            for (int c2 = 0; c2 < 16; ++c2) {
                int idx = (s2 * 16 + c2) * 32 + dl2;
                unsigned wv = PFR[idx];
                float pv = __uint_as_float(wv << 16);
                float fv = __uint_as_float(wv & 0xFFFF0000u);
                ((float*)PFR)[idx] = hh;
                hh = fv + pv * hh;
            }
        }
        __syncthreads();   // barrier #4
        float q[16];
#pragma unroll
        for (int s = 0; s < 16; ++s) q[s] = ((float*)PFR)[(s * 16 + cc) * 32 + dl];
        float S2 = 0.f;
#pragma unroll
        for (int k = 0; k < 16; ++k) {
            int i = i0 + k;
            int tt = dir ? 255 - i : i;
            float dt_ = bf2f_s(DTs[tt * DTL + dl]);
            S2 += dt_;
            float w1 = exp2f(S2 * A0c);
            float Cv[16];
            load16f(&Csm[i * 16], Cv);
            float g0 = Cv[0] * q[0], g1 = Cv[1] * q[1], g2 = Cv[2] * q[2], g3 = Cv[3] * q[3];
            float g4 = Cv[4] * q[4], g5 = Cv[5] * q[5], g6 = Cv[6] * q[6], g7 = Cv[7] * q[7];
            float g8 = Cv[8] * q[8], g9 = Cv[9] * q[9], g10 = Cv[10] * q[10], g11 = Cv[11] * q[11];
            float g12 = Cv[12] * q[12], g13 = Cv[13] * q[13], g14 = Cv[14] * q[14], g15 = Cv[15] * q[15];
            float w2 = w1 * w1, w4 = w2 * w2, w8 = w4 * w4;
            float e0 = fmaf(g1, w1, g0), e1 = fmaf(g3, w1, g2);
            float e2 = fmaf(g5, w1, g4), e3 = fmaf(g7, w1, g6);
            float e4 = fmaf(g9, w1, g8), e5 = fmaf(g11, w1, g10);
            float e6 = fmaf(g13, w1, g12), e7 = fmaf(g15, w1, g14);
            float f0 = fmaf(e1, w2, e0), f1 = fmaf(e3, w2, e2);
            float f2 = fmaf(e5, w2, e4), f3 = fmaf(e7, w2, e6);
            float r0 = fmaf(f1, w4, f0), r1 = fmaf(f3, w4, f2);
            float P = fmaf(r1, w8, r0);
            yp0[k * dstep] = __float2bfloat16(fmaf(P, w1, yl[k]));
        }
    } else {
        // ---- generic fallback (correctness path) ----
        float A2[16];
        {
            const float* ap = Alog + d * 16;
#pragma unroll
            for (int s = 0; s < 16; ++s) A2[s] = -__expf(ap[s]) * 1.44269504f;
        }
        float h[16];
#pragma unroll
        for (int s = 0; s < 16; ++s) h[s] = 0.f;
        float S = 0.f;
        {
            __hip_bfloat16* yp = yp0;
#pragma unroll
            for (int k = 0; k < 16; ++k) {
                int i = i0 + k;
                int tt = dir ? 255 - i : i;
                float dt_ = bf2f_s(DTs[tt * DTL + dl]);
                float uv = ureg[k];
                S += dt_;
                float du = dt_ * uv;
                float Bv[16], Cv[16];
                unpack16(&Bsm[i * 16], Bv);
                load16f(&Csm[i * 16], Cv);
                float yv = uv * Dval;
#pragma unroll
                for (int s = 0; s < 16; ++s) {
                    h[s] = exp2f(dt_ * A2[s]) * h[s] + du * Bv[s];
                    yv = fmaf(Cv[s], h[s], yv);
                }
                *yp = __float2bfloat16(yv); yp += dstep;
            }
        }
#pragma unroll
        for (int s = 0; s < 16; ++s) {
            float Pv = exp2f(A2[s] * S);
            unsigned wrd = (unsigned)(unsigned short)f2bf(Pv) |
                           ((unsigned)(unsigned short)f2bf(h[s]) << 16);
            PFR[(s * 16 + cc) * 32 + dl] = wrd;
        }
        __syncthreads();
        {
            int s2 = tid >> 5, dl2 = tid & 31;
            float hh = 0.f;
#pragma unroll
            for (int c2 = 0; c2 < 16; ++c2) {
                int idx = (s2 * 16 + c2) * 32 + dl2;
                unsigned wv = PFR[idx];
                float pv = __uint_as_float(wv << 16);
                float fv = __uint_as_float(wv & 0xFFFF0000u);
                ((float*)PFR)[idx] = hh;
                hh = fv + pv * hh;
            }
        }
        __syncthreads();
        float q[16];
#pragma unroll
        for (int s = 0; s < 16; ++s) q[s] = ((float*)PFR)[(s * 16 + cc) * 32 + dl];
        __hip_bfloat16* yp = yp0;
        float S2 = 0.f;
#pragma unroll
        for (int k = 0; k < 16; ++k) {
            int i = i0 + k;
            int tt = dir ? 255 - i : i;
            float dt_ = bf2f_s(DTs[tt * DTL + dl]);
            S2 += dt_;
            float Cv[16];
            load16f(&Csm[i * 16], Cv);
            float corr = 0.f;
#pragma unroll
            for (int s = 0; s < 16; ++s) corr += Cv[s] * q[s] * exp2f(A2[s] * S2);
            float ycur = __bfloat162float(*yp);
            *yp = __float2bfloat16(ycur + corr);
            yp += dstep;
        }
    }
}

extern "C" void kernel_launch(void* const* d_in, const int* in_sizes, int n_in,
                              void* d_out, int out_size, void* d_ws, size_t ws_size,
                              hipStream_t stream) {
    const float* x        = (const float*)d_in[0];
    const int*   t        = (const int*)d_in[1];
    const float* patch_w  = (const float*)d_in[2];
    const float* patch_b  = (const float*)d_in[3];
    const float* tw1      = (const float*)d_in[4];
    const float* tb1      = (const float*)d_in[5];
    const float* tw2      = (const float*)d_in[6];
    const float* tb2      = (const float*)d_in[7];
    const float* norm_g   = (const float*)d_in[8];
    const float* norm_b   = (const float*)d_in[9];
    const float* inproj_w = (const float*)d_in[10];
    const float* conv_w   = (const float*)d_in[11];
    const float* conv_b   = (const float*)d_in[12];
    const float* Alog_f   = (const float*)d_in[13];
    const float* D_f      = (const float*)d_in[14];
    const float* xproj_f  = (const float*)d_in[15];
    const float* dtw_f    = (const float*)d_in[16];
    const float* dtb_f    = (const float*)d_in[17];
    const float* Alog_bk  = (const float*)d_in[18];
    const float* D_bk     = (const float*)d_in[19];
    const float* xproj_bk = (const float*)d_in[20];
    const float* dtw_bk   = (const float*)d_in[21];
    const float* dtb_bk   = (const float*)d_in[22];
    const float* outproj_w= (const float*)d_in[23];
    const float* fng      = (const float*)d_in[24];
    const float* fnb      = (const float*)d_in[25];
    const float* fin_w    = (const float*)d_in[26];
    const float* fin_b    = (const float*)d_in[27];
    float* out = (float*)d_out;

    char* base = (char*)d_ws;
    float*          te  = (float*)base;                                   // 16 KB
    float*          h   = (float*)(base + (16UL << 10));                  // 4 MB
    __hip_bfloat16* hn  = (__hip_bfloat16*)(base + (16UL << 10) + (4UL << 20));   // 2 MB
    __hip_bfloat16* xz  = (__hip_bfloat16*)((char*)hn + (2UL << 20));     // 8 MB
    __hip_bfloat16* uu  = (__hip_bfloat16*)((char*)xz + (8UL << 20));     // 4 MB
    float*          pf2 = (float*)((char*)uu + (4UL << 20));              // 2 MB
    __hip_bfloat16* y2  = (__hip_bfloat16*)((char*)pf2 + (2UL << 20));    // 8 MB
    __hip_bfloat16* wbf = (__hip_bfloat16*)((char*)y2 + (8UL << 20));     // 4 MB

    __hip_bfloat16* w_in  = wbf;
    __hip_bfloat16* w_xf  = wbf + 1048576;
    __hip_bfloat16* w_xb  = wbf + 1179648;
    __hip_bfloat16* w_dtf = wbf + 1310720;
    __hip_bfloat16* w_dtb = wbf + 1376256;
    __hip_bfloat16* w_out = wbf + 1441792;

    const int M = BB * LL;                // 4096

    cvt_w<<<1920, 256, 0, stream>>>(inproj_w, xproj_f, xproj_bk, dtw_f, dtw_bk,
                                    outproj_w, wbf);
    patch_embed<<<256, 256, 0, stream>>>(x, patch_w, patch_b, h);
    time_embed<<<BB, 256, 0, stream>>>(t, tw1, tb1, tw2, tb2, te);

    for (int i = 0; i < 4; ++i) {
        ln_kernel<__hip_bfloat16><<<M, 256, 0, stream>>>(
            h, te, norm_g + i * 256, norm_b + i * 256, hn);
        gemm_mfma<128, 128, 2, 2, 4, 4, 0, false, false, 0, true><<<dim3(32, 8), 256, 0, stream>>>(
            hn, w_in + (size_t)i * 262144, nullptr, xz, M, 1024, 256, 256,
            nullptr, nullptr, nullptr, 0);
        conv_silu<<<1024, 256, 0, stream>>>(xz, conv_w + i * 2048, conv_b + i * 512, uu);
        gemm_mfma<32, 64, 2, 2, 1, 2, 0, false, false, 0, false><<<dim3(128, 2), 256, 0, stream>>>(
            uu, w_xf + (size_t)i * 32768, nullptr, pf2, M, 128, 512, 512,
            uu, w_xb + (size_t)i * 32768, nullptr, 64);
        scan_fused<<<512, 512, 0, stream>>>(uu, pf2,
            w_dtf + (size_t)i * 16384, w_dtb + (size_t)i * 16384,
            dtb_f + i * 512, dtb_bk + i * 512,
            Alog_f + (size_t)i * 8192, Alog_bk + (size_t)i * 8192,
            D_f + i * 512, D_bk + i * 512, y2);
        gemm_mfma<64, 64, 4, 1, 1, 4, 0, true, false, 2, false><<<dim3(64, 4), 256, 0, stream>>>(
            y2, w_out + (size_t)i * 131072, nullptr, h, M, 256, 512, 1024,
            xz, nullptr, nullptr, 0);
    }

    head_fused<<<64, 256, 0, stream>>>(h, fng, fnb, fin_w, fin_b, out);
}

// Round 14
// 442.786 us; speedup vs baseline: 1.0194x; 1.0194x over previous
//
#include <hip/hip_runtime.h>
#include <hip/hip_bf16.h>

#define BB 16
#define LL 256
#define DD 256
#define DI 512
#define DS 16

typedef __attribute__((ext_vector_type(8))) short bf16x8;
typedef __attribute__((ext_vector_type(4))) short bf16x4;
typedef __attribute__((ext_vector_type(4))) float f32x4;

__device__ inline short f2bf(float f) {
    __hip_bfloat16 h = __float2bfloat16(f);
    return *reinterpret_cast<short*>(&h);
}
__device__ inline float bf2f_s(short s) {
    __hip_bfloat16 h = *reinterpret_cast<__hip_bfloat16*>(&s);
    return __bfloat162float(h);
}
__device__ inline void stf(float* p, float v) { *p = v; }
__device__ inline void stf(__hip_bfloat16* p, float v) { *p = __float2bfloat16(v); }

// unpack 16 contiguous bf16 from LDS into 16 floats
__device__ inline void unpack16(const short* p, float* f) {
    bf16x8 v0 = *(const bf16x8*)p;
    bf16x8 v1 = *(const bf16x8*)(p + 8);
    const unsigned* a = (const unsigned*)&v0;
    const unsigned* b = (const unsigned*)&v1;
#pragma unroll
    for (int j = 0; j < 4; ++j) {
        f[2 * j]     = __uint_as_float(a[j] << 16);
        f[2 * j + 1] = __uint_as_float(a[j] & 0xFFFF0000u);
        f[8 + 2 * j]     = __uint_as_float(b[j] << 16);
        f[8 + 2 * j + 1] = __uint_as_float(b[j] & 0xFFFF0000u);
    }
}
// load 16 f32 from LDS
__device__ inline void load16f(const float* p, float* f) {
    const f32x4* cp = (const f32x4*)p;
    f32x4 c0 = cp[0], c1 = cp[1], c2 = cp[2], c3 = cp[3];
    f[0]=c0[0]; f[1]=c0[1]; f[2]=c0[2]; f[3]=c0[3];
    f[4]=c1[0]; f[5]=c1[1]; f[6]=c1[2]; f[7]=c1[3];
    f[8]=c2[0]; f[9]=c2[1]; f[10]=c2[2]; f[11]=c2[3];
    f[12]=c3[0]; f[13]=c3[1]; f[14]=c3[2]; f[15]=c3[3];
}

// ---------------- weight fp32->bf16 pre-convert (once per call) ----------------
__global__ __launch_bounds__(256) void cvt_w(
    const float* __restrict__ s0, const float* __restrict__ s1,
    const float* __restrict__ s2, const float* __restrict__ s3,
    const float* __restrict__ s4, const float* __restrict__ s5,
    __hip_bfloat16* __restrict__ dst) {
    int i = blockIdx.x * 256 + threadIdx.x;      // vec4 index
    if (i >= 491520) return;
    int e = i * 4;
    const float* src; int off;
    if (e < 1048576)      { src = s0; off = e; }
    else if (e < 1179648) { src = s1; off = e - 1048576; }
    else if (e < 1310720) { src = s2; off = e - 1179648; }
    else if (e < 1376256) { src = s3; off = e - 1310720; }
    else if (e < 1441792) { src = s4; off = e - 1376256; }
    else                  { src = s5; off = e - 1441792; }
    float4 v = *(const float4*)(src + off);
    bf16x4 r;
    r[0] = f2bf(v.x); r[1] = f2bf(v.y); r[2] = f2bf(v.z); r[3] = f2bf(v.w);
    *(bf16x4*)((short*)dst + e) = r;
}

// ---------------- patch embed ----------------
__global__ __launch_bounds__(256) void patch_embed(const float* __restrict__ x,
                                                   const float* __restrict__ pw,
                                                   const float* __restrict__ pb,
                                                   float* __restrict__ h) {
    int blk = blockIdx.x;           // b*16 + lg
    int b = blk >> 4, lg = blk & 15;
    int tid = threadIdx.x;
    __shared__ float pws[48 * 258];
    __shared__ float xs[16][48];
    for (int it = 0; it < 48; ++it) {
        int idx = tid + it * 256;
        float v = pw[idx];
        int dd = idx / 48, k = idx - dd * 48;
        pws[k * 258 + dd] = v;
    }
    for (int idx = tid; idx < 16 * 48; idx += 256) {
        int li = idx / 48, k = idx - li * 48;
        int c = k >> 4, py = (k >> 2) & 3, px = k & 3;
        xs[li][k] = x[(size_t)(b * 3 + c) * 4096 + (lg * 4 + py) * 64 + li * 4 + px];
    }
    __syncthreads();
    float bv = pb[tid];
#pragma unroll 4
    for (int li = 0; li < 16; ++li) {
        float acc = bv;
#pragma unroll
        for (int k = 0; k < 48; ++k) acc += xs[li][k] * pws[k * 258 + tid];
        h[((size_t)(b * 256 + lg * 16 + li)) * 256 + tid] = acc;
    }
}

// ---------------- time embedding ----------------
__global__ void time_embed(const int* __restrict__ t, const float* __restrict__ tw1,
                           const float* __restrict__ tb1, const float* __restrict__ tw2,
                           const float* __restrict__ tb2, float* __restrict__ te) {
    int b = blockIdx.x, j = threadIdx.x;
    __shared__ float s0[256], s1[256];
    float tv = (float)t[b];
    if (j < 128) {
        float f = expf((float)j * (-9.210340371976184f / 127.f));
        float a = tv * f;
        s0[j] = sinf(a);
        s0[j + 128] = cosf(a);
    }
    __syncthreads();
    float acc = tb1[j];
    for (int k = 0; k < 256; ++k) acc += s0[k] * tw1[j * 256 + k];
    s1[j] = acc / (1.f + expf(-acc));
    __syncthreads();
    float acc2 = tb2[j];
    for (int k = 0; k < 256; ++k) acc2 += s1[k] * tw2[j * 256 + k];
    te[b * 256 + j] = acc2;
}

// ---------------- layernorm (per-layer, +te) ----------------
template <typename TO>
__global__ void ln_kernel(const float* __restrict__ h, const float* __restrict__ te,
                          const float* __restrict__ g, const float* __restrict__ bta,
                          TO* __restrict__ out) {
    int row = blockIdx.x;
    int b = row >> 8;
    int d = threadIdx.x;
    float v = h[(size_t)row * 256 + d] + (te ? te[b * 256 + d] : 0.f);
    float s = v, s2 = v * v;
#pragma unroll
    for (int o = 32; o; o >>= 1) {
        s += __shfl_down(s, o, 64);
        s2 += __shfl_down(s2, o, 64);
    }
    __shared__ float ws[4], ws2[4];
    int wid = threadIdx.x >> 6, lane = threadIdx.x & 63;
    if (lane == 0) { ws[wid] = s; ws2[wid] = s2; }
    __syncthreads();
    float mu = (ws[0] + ws[1] + ws[2] + ws[3]) * (1.f / 256.f);
    float m2 = (ws2[0] + ws2[1] + ws2[2] + ws2[3]) * (1.f / 256.f);
    float var = m2 - mu * mu;
    stf(&out[(size_t)row * 256 + d], (v - mu) * rsqrtf(var + 1e-5f) * g[d] + bta[d]);
}

// ---------------- bf16 MFMA GEMM (bf16 weights) ----------------
template <int BM, int BN, int WM, int WN, int FM, int FN, int ACT, bool ADD,
          bool HASBIAS, int AMODE, bool OBF>
__global__ __launch_bounds__(256) void gemm_mfma(
    const void* __restrict__ Ap, const __hip_bfloat16* __restrict__ W,
    const float* __restrict__ bias, void* __restrict__ Cp,
    int M, int N, int K, int lda,
    const void* __restrict__ A2p, const __hip_bfloat16* __restrict__ W2,
    const float* __restrict__ bias2, int nsplit)
{
    constexpr int LDP = 40;
    __shared__ __align__(16) short As[BM * LDP];
    __shared__ __align__(16) short Ws[BN * LDP];
    int tid = threadIdx.x;
    int lane = tid & 63;
    int w = tid >> 6;
    int wm, wn;
    if (WN == 1) { wm = w; wn = 0; } else { wm = w >> 1; wn = w & 1; }
    int m0 = blockIdx.x * BM;
    int n0 = blockIdx.y * BN;
    int wn0 = n0;
    if (nsplit > 0 && n0 >= nsplit) { Ap = A2p; W = W2; bias = bias2; wn0 = n0 - nsplit; }

    f32x4 acc[FM][FN];
#pragma unroll
    for (int i = 0; i < FM; ++i)
#pragma unroll
        for (int j = 0; j < FN; ++j) acc[i][j] = (f32x4){0.f, 0.f, 0.f, 0.f};

    for (int k0 = 0; k0 < K; k0 += 32) {
        if (AMODE == 0) {
            for (int idx = tid; idx < BM * 4; idx += 256) {
                int row = idx >> 2, qc = idx & 3;
                const __hip_bfloat16* g = (const __hip_bfloat16*)Ap +
                    (size_t)(m0 + row) * lda + k0 + qc * 8;
                *(bf16x8*)&As[row * LDP + qc * 8] = *(const bf16x8*)g;
            }
        } else if (AMODE == 1) {
            for (int idx = tid; idx < BM * 4; idx += 256) {
                int row = idx >> 2, qc = idx & 3;
                const float* g = (const float*)Ap + (size_t)(m0 + row) * lda + k0 + qc * 8;
                float4 v0 = *(const float4*)g;
                float4 v1 = *(const float4*)(g + 4);
                union { bf16x8 v; short s[8]; } u8;
                u8.s[0] = f2bf(v0.x); u8.s[1] = f2bf(v0.y); u8.s[2] = f2bf(v0.z); u8.s[3] = f2bf(v0.w);
                u8.s[4] = f2bf(v1.x); u8.s[5] = f2bf(v1.y); u8.s[6] = f2bf(v1.z); u8.s[7] = f2bf(v1.w);
                *(bf16x8*)&As[row * LDP + qc * 8] = u8.v;
            }
        } else {
            for (int idx = tid; idx < BM * 4; idx += 256) {
                int row = idx >> 2, qc = idx & 3;
                size_t rb = (size_t)(m0 + row) * 1024 + k0 + qc * 8;
                union { bf16x8 v; short s[8]; } uf, ub, uz, r;
                uf.v = *(const bf16x8*)((const __hip_bfloat16*)Ap + rb);
                ub.v = *(const bf16x8*)((const __hip_bfloat16*)Ap + rb + 512);
                uz.v = *(const bf16x8*)((const __hip_bfloat16*)A2p + rb + 512);
#pragma unroll
                for (int e = 0; e < 8; ++e) {
                    float z = bf2f_s(uz.s[e]);
                    float sg = z / (1.f + __expf(-z));
                    r.s[e] = f2bf((bf2f_s(uf.s[e]) + bf2f_s(ub.s[e])) * sg);
                }
                *(bf16x8*)&As[row * LDP + qc * 8] = r.v;
            }
        }
        for (int idx = tid; idx < BN * 4; idx += 256) {
            int row = idx >> 2, qc = idx & 3;
            const __hip_bfloat16* g = W + (size_t)(wn0 + row) * K + k0 + qc * 8;
            *(bf16x8*)&Ws[row * LDP + qc * 8] = *(const bf16x8*)g;
        }
        __syncthreads();
        int kg = lane >> 4, r = lane & 15;
        bf16x8 af[FM], bfr[FN];
#pragma unroll
        for (int i = 0; i < FM; ++i)
            af[i] = *(const bf16x8*)&As[(wm * FM * 16 + i * 16 + r) * LDP + kg * 8];
#pragma unroll
        for (int j = 0; j < FN; ++j)
            bfr[j] = *(const bf16x8*)&Ws[(wn * FN * 16 + j * 16 + r) * LDP + kg * 8];
#pragma unroll
        for (int i = 0; i < FM; ++i)
#pragma unroll
            for (int j = 0; j < FN; ++j)
                acc[i][j] = __builtin_amdgcn_mfma_f32_16x16x32_bf16(af[i], bfr[j], acc[i][j], 0, 0, 0);
        __syncthreads();
    }
    int r = lane & 15, qg = lane >> 4;
#pragma unroll
    for (int i = 0; i < FM; ++i) {
#pragma unroll
        for (int j = 0; j < FN; ++j) {
            int col = n0 + wn * FN * 16 + j * 16 + r;
            int colw = wn0 + wn * FN * 16 + j * 16 + r;
            float bv = HASBIAS ? bias[colw] : 0.f;
#pragma unroll
            for (int q = 0; q < 4; ++q) {
                int rowm = m0 + wm * FM * 16 + i * 16 + qg * 4 + q;
                float v = acc[i][j][q] + bv;
                if (ACT == 1) v = (v > 20.f) ? v : log1pf(__expf(v));
                size_t o = (size_t)rowm * N + col;
                if (OBF) ((__hip_bfloat16*)Cp)[o] = __float2bfloat16(v);
                else if (ADD) ((float*)Cp)[o] += v;
                else ((float*)Cp)[o] = v;
            }
        }
    }
}

// ---------------- head: fused final-LN + GEMM + unpatchify ----------------
__global__ __launch_bounds__(256) void head_fused(
    const float* __restrict__ A, const float* __restrict__ fng,
    const float* __restrict__ fnb, const float* __restrict__ W,
    const float* __restrict__ bias, float* __restrict__ C) {
    __shared__ float Asm[16][65];
    __shared__ float Wsm[16][65];
    __shared__ float mu_s[64], rs_s[64];
    __shared__ float red[256], red2[256];
    int tid = threadIdx.x;
    int m0 = blockIdx.x * 64;
    {
        int rr = tid >> 2, part = tid & 3;
        const float* hrow = A + (size_t)(m0 + rr) * 256 + part * 64;
        float s = 0.f, s2 = 0.f;
#pragma unroll
        for (int j = 0; j < 16; ++j) {
            float4 v = *(const float4*)(hrow + j * 4);
            s += v.x + v.y + v.z + v.w;
            s2 += v.x * v.x + v.y * v.y + v.z * v.z + v.w * v.w;
        }
        red[tid] = s; red2[tid] = s2;
    }
    __syncthreads();
    if ((tid & 3) == 0) {
        int rr = tid >> 2;
        float S = red[tid] + red[tid + 1] + red[tid + 2] + red[tid + 3];
        float S2 = red2[tid] + red2[tid + 1] + red2[tid + 2] + red2[tid + 3];
        float mu = S * (1.f / 256.f);
        float var = S2 * (1.f / 256.f) - mu * mu;
        mu_s[rr] = mu;
        rs_s[rr] = rsqrtf(var + 1e-5f);
    }
    __syncthreads();
    int tx = tid & 15, ty = tid >> 4;
    float acc[4][4] = {};
    for (int k0 = 0; k0 < 256; k0 += 16) {
#pragma unroll
        for (int i = 0; i < 4; ++i) {
            int idx = tid + i * 256;
            int rr = idx >> 4, cc = idx & 15;
            float v = A[(size_t)(m0 + rr) * 256 + k0 + cc];
            Asm[cc][rr] = (v - mu_s[rr]) * rs_s[rr] * fng[k0 + cc] + fnb[k0 + cc];
            Wsm[cc][rr] = (rr < 48) ? W[(size_t)rr * 256 + k0 + cc] : 0.f;
        }
        __syncthreads();
#pragma unroll
        for (int k = 0; k < 16; ++k) {
            float av[4], wv[4];
#pragma unroll
            for (int i = 0; i < 4; ++i) av[i] = Asm[k][ty * 4 + i];
#pragma unroll
            for (int j = 0; j < 4; ++j) wv[j] = Wsm[k][tx * 4 + j];
#pragma unroll
            for (int i = 0; i < 4; ++i)
#pragma unroll
                for (int j = 0; j < 4; ++j) acc[i][j] += av[i] * wv[j];
        }
        __syncthreads();
    }
#pragma unroll
    for (int i = 0; i < 4; ++i) {
        int m = m0 + ty * 4 + i;
#pragma unroll
        for (int j = 0; j < 4; ++j) {
            int n = tx * 4 + j;
            if (n < 48) {
                float v = acc[i][j] + bias[n];
                int b = m >> 8, l = m & 255;
                int c = n >> 4;
                int hy = ((l >> 4) << 2) + ((n >> 2) & 3);
                int wx = ((l & 15) << 2) + (n & 3);
                C[(size_t)(b * 3 + c) * 4096 + hy * 64 + wx] = v;
            }
        }
    }
}

// ---------------- causal depthwise conv (k=4) + silu ----------------
__global__ __launch_bounds__(256) void conv_silu(
    const __hip_bfloat16* __restrict__ xz, const float* __restrict__ cw,
    const float* __restrict__ cb, __hip_bfloat16* __restrict__ u) {
    int g = blockIdx.x * 4 + (threadIdx.x >> 6);
    int lane = threadIdx.x & 63;
    int l = g & 255;
    int d0 = lane * 8;
    const __hip_bfloat16* base = xz + (size_t)g * 1024 + d0;
    union { bf16x8 v; short s[8]; } t0, t1, t2, t3, r;
    bf16x8 zz = {};
    t3.v = *(const bf16x8*)base;
    t2.v = (l >= 1) ? *(const bf16x8*)(base - 1024) : zz;
    t1.v = (l >= 2) ? *(const bf16x8*)(base - 2048) : zz;
    t0.v = (l >= 3) ? *(const bf16x8*)(base - 3072) : zz;
#pragma unroll
    for (int e = 0; e < 8; ++e) {
        int d = d0 + e;
        const float4 wv = *(const float4*)(cw + d * 4);
        float acc = cb[d] + bf2f_s(t0.s[e]) * wv.x + bf2f_s(t1.s[e]) * wv.y +
                    bf2f_s(t2.s[e]) * wv.z + bf2f_s(t3.s[e]) * wv.w;
        r.s[e] = f2bf(acc / (1.f + __expf(-acc)));
    }
    *(bf16x8*)(u + (size_t)g * 512 + d0) = r.v;
}

// ================= fused SSM scan v12: 256-thread blocks, 3/CU residency =================
// 1024 blocks (XCD-swizzled), 256 threads = 16 chunks (cc) x 16 channels (dl).
// Phased LDS union: {dtp+dtw staging} dies at MFMA barrier -> {Csm f32 | PFR}.
// Total LDS ~50 KB -> 3 blocks/CU capacity; whole grid resident in ~1.3 rounds.
__global__ __launch_bounds__(256) void scan_fused(
    const __hip_bfloat16* __restrict__ u, const float* __restrict__ pf2,
    const __hip_bfloat16* __restrict__ dtwF, const __hip_bfloat16* __restrict__ dtwB,
    const float* __restrict__ dtbF, const float* __restrict__ dtbB,
    const float* __restrict__ Alog_f, const float* __restrict__ Alog_b,
    const float* __restrict__ Dv_f, const float* __restrict__ Dv_b,
    __hip_bfloat16* __restrict__ y2)
{
    int blk = blockIdx.x;
    int c8 = blk & 7, idxb = blk >> 3;   // idxb 0..127
    int bd = c8 + 8 * (idxb & 3);        // XCD swizzle: same bd -> same XCD
    int dg = idxb >> 2;                  // 0..31, selects 16 channels
    int dir = bd & 1, b = bd >> 1;
    int tid = threadIdx.x;
    int dl = tid & 15, cc = tid >> 4;
    int d0 = dg * 16;
    int d = d0 + dl;
    int poff = dir ? 64 : 0;
    int doff = dir ? 512 : 0;
    const float* Alog = dir ? Alog_b : Alog_f;
    float Dval = (dir ? Dv_b : Dv_f)[d];
    const __hip_bfloat16* dtw = dir ? dtwB : dtwF;
    const float* dtb = dir ? dtbB : dtbF;

    constexpr int DTL = 18;                          // padded stride
    __shared__ __align__(16) short DTs[256 * DTL];   // 9.2 KB
    __shared__ __align__(16) short Bsm[256 * 16];    // 8 KB bf16 (scan order)
    __shared__ __align__(16) char UR[32768];         // 32 KB phased union
    float*    Csm  = (float*)UR;                     // 16 KB (staged AFTER MFMA)
    unsigned* PFR  = (unsigned*)(UR + 16384);        // 16 KB (P|F packed, then Hin)
    short*    dtpL = (short*)UR;                     // 20.5 KB (staging phase only)
    short*    dtwL = (short*)(UR + 20480);           // 1.28 KB

    int i0 = cc * 16;
    int row0 = b * 256 + (dir ? 255 - i0 : i0);
    int stpE = dir ? -1 : 1;
    int dstep = stpE * 1024, ustep = stpE * 512;
    const __hip_bfloat16* up0 = u + (size_t)row0 * 512 + d;
    __hip_bfloat16* yp0 = y2 + (size_t)row0 * 1024 + doff + d;

    // ---- u into registers (own chunk, own channel) ----
    float ureg[16];
#pragma unroll
    for (int k = 0; k < 16; ++k) ureg[k] = __bfloat162float(up0[k * ustep]);

    // ---- staging phase 1: B (scan order), dtp, dtw ----
    for (int idx = tid; idx < 512; idx += 256) {     // B bf16: 256 rows x 2 halves
        int i = idx >> 1, half = idx & 1;
        int tt = dir ? 255 - i : i;
        const float* pr = pf2 + ((size_t)b * 256 + tt) * 128 + poff + 32 + half * 8;
        float4 v0 = *(const float4*)pr;
        float4 v1 = *(const float4*)(pr + 4);
        union { bf16x8 v; short s[8]; } u8;
        u8.s[0] = f2bf(v0.x); u8.s[1] = f2bf(v0.y); u8.s[2] = f2bf(v0.z); u8.s[3] = f2bf(v0.w);
        u8.s[4] = f2bf(v1.x); u8.s[5] = f2bf(v1.y); u8.s[6] = f2bf(v1.z); u8.s[7] = f2bf(v1.w);
        *(bf16x8*)&Bsm[i * 16 + half * 8] = u8.v;
    }
    for (int idx = tid; idx < 1024; idx += 256) {    // dtp (raw row order), 8 floats/iter
        int row = idx >> 2, q = idx & 3;
        const float* pr = pf2 + ((size_t)(b * 256 + row)) * 128 + poff + q * 8;
        float4 v0 = *(const float4*)pr;
        float4 v1 = *(const float4*)(pr + 4);
        union { bf16x8 v; short s[8]; } u8;
        u8.s[0] = f2bf(v0.x); u8.s[1] = f2bf(v0.y); u8.s[2] = f2bf(v0.z); u8.s[3] = f2bf(v0.w);
        u8.s[4] = f2bf(v1.x); u8.s[5] = f2bf(v1.y); u8.s[6] = f2bf(v1.z); u8.s[7] = f2bf(v1.w);
        *(bf16x8*)&dtpL[row * 40 + q * 8] = u8.v;
    }
    if (tid < 64) {                                  // dtw rows d0..d0+15 (already bf16)
        int row = tid >> 2, q = tid & 3;
        *(bf16x8*)&dtwL[row * 40 + q * 8] =
            *(const bf16x8*)(dtw + (size_t)(d0 + row) * 32 + q * 8);
    }
    // ---- A-structure check ----
    float A0c;
    int okl = 1;
    {
        const float* ap = Alog + d * 16;
        float A0 = -__expf(ap[0]);
        A0c = A0 * 1.44269504f;
#pragma unroll
        for (int s = 1; s < 16; ++s) {
            float As_ = -__expf(ap[s]);
            okl = okl && (fabsf(As_ - (float)(s + 1) * A0) <= 1e-3f * (float)(s + 1));
        }
    }
    bool fast = __syncthreads_and(okl) != 0;   // barrier #1: staging visible + vote

    // ---- dt via MFMA: 16 row-tiles x 1 col-tile, 4 waves x 4 MFMAs ----
    {
        int w = tid >> 6, lane = tid & 63;
        int r = lane & 15, kg = lane >> 4;
#pragma unroll
        for (int p = 0; p < 4; ++p) {
            int t = w * 4 + p;
            bf16x8 af = *(const bf16x8*)&dtpL[(t * 16 + r) * 40 + kg * 8];
            bf16x8 bfr = *(const bf16x8*)&dtwL[r * 40 + kg * 8];
            f32x4 acc = (f32x4){0.f, 0.f, 0.f, 0.f};
            acc = __builtin_amdgcn_mfma_f32_16x16x32_bf16(af, bfr, acc, 0, 0, 0);
            float bvv = dtb[d0 + r];
#pragma unroll
            for (int q = 0; q < 4; ++q) {
                int rowl = t * 16 + kg * 4 + q;
                float vdt = acc[q] + bvv;
                vdt = (vdt > 20.f) ? vdt : log1pf(__expf(vdt));
                DTs[rowl * DTL + r] = f2bf(vdt);
            }
        }
    }
    __syncthreads();   // barrier #2: DT done, dtp/dtw dead

    // ---- staging phase 2: C f32 into freed region ----
    for (int idx = tid; idx < 1024; idx += 256) {
        int i = idx >> 2, q = idx & 3;
        int tt = dir ? 255 - i : i;
        *(f32x4*)&Csm[i * 16 + q * 4] =
            *(const f32x4*)(pf2 + ((size_t)b * 256 + tt) * 128 + poff + 48 + q * 4);
    }
    __syncthreads();   // barrier #2b: Csm visible

    if (fast) {
        float h[16], yl[16];
#pragma unroll
        for (int s = 0; s < 16; ++s) h[s] = 0.f;
        float S = 0.f;
        // ---- Pass A: tree powers, 4-acc y-sum ----
#pragma unroll
        for (int k = 0; k < 16; ++k) {
            int i = i0 + k;
            int tt = dir ? 255 - i : i;
            float dt_ = bf2f_s(DTs[tt * DTL + dl]);
            S += dt_;
            float du = dt_ * ureg[k];
            float Bv[16], Cv[16];
            unpack16(&Bsm[i * 16], Bv);
            load16f(&Csm[i * 16], Cv);
            float p1 = exp2f(dt_ * A0c);
            float y0, y1_, y2_, y3;
            float p2 = p1 * p1;
            float p3 = p2 * p1;
            float p4 = p2 * p2;
            float p5 = p4 * p1;
            float p6 = p4 * p2;
            float p7 = p4 * p3;
            float p8 = p4 * p4;
            h[0] = p1 * h[0] + du * Bv[0];  y0 = Cv[0] * h[0];
            h[1] = p2 * h[1] + du * Bv[1];  y1_ = Cv[1] * h[1];
            h[2] = p3 * h[2] + du * Bv[2];  y2_ = Cv[2] * h[2];
            h[3] = p4 * h[3] + du * Bv[3];  y3 = Cv[3] * h[3];
            h[4] = p5 * h[4] + du * Bv[4];  y0 = fmaf(Cv[4], h[4], y0);
            h[5] = p6 * h[5] + du * Bv[5];  y1_ = fmaf(Cv[5], h[5], y1_);
            h[6] = p7 * h[6] + du * Bv[6];  y2_ = fmaf(Cv[6], h[6], y2_);
            h[7] = p8 * h[7] + du * Bv[7];  y3 = fmaf(Cv[7], h[7], y3);
            h[8] = p8 * p1 * h[8] + du * Bv[8];    y0 = fmaf(Cv[8], h[8], y0);
            h[9] = p8 * p2 * h[9] + du * Bv[9];    y1_ = fmaf(Cv[9], h[9], y1_);
            h[10] = p8 * p3 * h[10] + du * Bv[10]; y2_ = fmaf(Cv[10], h[10], y2_);
            h[11] = p8 * p4 * h[11] + du * Bv[11]; y3 = fmaf(Cv[11], h[11], y3);
            h[12] = p8 * p5 * h[12] + du * Bv[12]; y0 = fmaf(Cv[12], h[12], y0);
            h[13] = p8 * p6 * h[13] + du * Bv[13]; y1_ = fmaf(Cv[13], h[13], y1_);
            h[14] = p8 * p7 * h[14] + du * Bv[14]; y2_ = fmaf(Cv[14], h[14], y2_);
            h[15] = p8 * p8 * h[15] + du * Bv[15]; y3 = fmaf(Cv[15], h[15], y3);
            yl[k] = fmaf(ureg[k], Dval, (y0 + y1_) + (y2_ + y3));
        }
        // chunk decay W^(s+1) via tree
        {
            float W1 = exp2f(S * A0c);
            float W2 = W1 * W1, W3 = W2 * W1, W4 = W2 * W2;
            float W5 = W4 * W1, W6 = W4 * W2, W7 = W4 * W3, W8 = W4 * W4;
            float Pv[16] = {W1, W2, W3, W4, W5, W6, W7, W8,
                            W8 * W1, W8 * W2, W8 * W3, W8 * W4,
                            W8 * W5, W8 * W6, W8 * W7, W8 * W8};
#pragma unroll
            for (int s = 0; s < 16; ++s) {
                unsigned wrd = (unsigned)(unsigned short)f2bf(Pv[s]) |
                               ((unsigned)(unsigned short)f2bf(h[s]) << 16);
                PFR[(s * 16 + cc) * 16 + dl] = wrd;
            }
        }
        __syncthreads();   // barrier #3
        {
            int s2 = tid >> 4, dl2 = tid & 15;
            float hh = 0.f;
#pragma unroll
            for (int c2 = 0; c2 < 16; ++c2) {
                int idx = (s2 * 16 + c2) * 16 + dl2;
                unsigned wv = PFR[idx];
                float pv = __uint_as_float(wv << 16);
                float fv = __uint_as_float(wv & 0xFFFF0000u);
                ((float*)PFR)[idx] = hh;
                hh = fv + pv * hh;
            }
        }
        __syncthreads();   // barrier #4
        // ---- Pass B: Estrin correction, single y write ----
        float q[16];
#pragma unroll
        for (int s = 0; s < 16; ++s) q[s] = ((float*)PFR)[(s * 16 + cc) * 16 + dl];
        float S2 = 0.f;
#pragma unroll
        for (int k = 0; k < 16; ++k) {
            int i = i0 + k;
            int tt = dir ? 255 - i : i;
            float dt_ = bf2f_s(DTs[tt * DTL + dl]);
            S2 += dt_;
            float w1 = exp2f(S2 * A0c);
            float Cv[16];
            load16f(&Csm[i * 16], Cv);
            float g0 = Cv[0] * q[0], g1 = Cv[1] * q[1], g2 = Cv[2] * q[2], g3 = Cv[3] * q[3];
            float g4 = Cv[4] * q[4], g5 = Cv[5] * q[5], g6 = Cv[6] * q[6], g7 = Cv[7] * q[7];
            float g8 = Cv[8] * q[8], g9 = Cv[9] * q[9], g10 = Cv[10] * q[10], g11 = Cv[11] * q[11];
            float g12 = Cv[12] * q[12], g13 = Cv[13] * q[13], g14 = Cv[14] * q[14], g15 = Cv[15] * q[15];
            float w2 = w1 * w1, w4 = w2 * w2, w8 = w4 * w4;
            float e0 = fmaf(g1, w1, g0), e1 = fmaf(g3, w1, g2);
            float e2 = fmaf(g5, w1, g4), e3 = fmaf(g7, w1, g6);
            float e4 = fmaf(g9, w1, g8), e5 = fmaf(g11, w1, g10);
            float e6 = fmaf(g13, w1, g12), e7 = fmaf(g15, w1, g14);
            float f0 = fmaf(e1, w2, e0), f1 = fmaf(e3, w2, e2);
            float f2 = fmaf(e5, w2, e4), f3 = fmaf(e7, w2, e6);
            float r0 = fmaf(f1, w4, f0), r1 = fmaf(f3, w4, f2);
            float P = fmaf(r1, w8, r0);
            yp0[k * dstep] = __float2bfloat16(fmaf(P, w1, yl[k]));
        }
    } else {
        // ---- generic fallback (correctness path) ----
        float A2[16];
        {
            const float* ap = Alog + d * 16;
#pragma unroll
            for (int s = 0; s < 16; ++s) A2[s] = -__expf(ap[s]) * 1.44269504f;
        }
        float h[16];
#pragma unroll
        for (int s = 0; s < 16; ++s) h[s] = 0.f;
        float S = 0.f;
        {
            __hip_bfloat16* yp = yp0;
#pragma unroll
            for (int k = 0; k < 16; ++k) {
                int i = i0 + k;
                int tt = dir ? 255 - i : i;
                float dt_ = bf2f_s(DTs[tt * DTL + dl]);
                float uv = ureg[k];
                S += dt_;
                float du = dt_ * uv;
                float Bv[16], Cv[16];
                unpack16(&Bsm[i * 16], Bv);
                load16f(&Csm[i * 16], Cv);
                float yv = uv * Dval;
#pragma unroll
                for (int s = 0; s < 16; ++s) {
                    h[s] = exp2f(dt_ * A2[s]) * h[s] + du * Bv[s];
                    yv = fmaf(Cv[s], h[s], yv);
                }
                *yp = __float2bfloat16(yv); yp += dstep;
            }
        }
#pragma unroll
        for (int s = 0; s < 16; ++s) {
            float Pv = exp2f(A2[s] * S);
            unsigned wrd = (unsigned)(unsigned short)f2bf(Pv) |
                           ((unsigned)(unsigned short)f2bf(h[s]) << 16);
            PFR[(s * 16 + cc) * 16 + dl] = wrd;
        }
        __syncthreads();
        {
            int s2 = tid >> 4, dl2 = tid & 15;
            float hh = 0.f;
#pragma unroll
            for (int c2 = 0; c2 < 16; ++c2) {
                int idx = (s2 * 16 + c2) * 16 + dl2;
                unsigned wv = PFR[idx];
                float pv = __uint_as_float(wv << 16);
                float fv = __uint_as_float(wv & 0xFFFF0000u);
                ((float*)PFR)[idx] = hh;
                hh = fv + pv * hh;
            }
        }
        __syncthreads();
        float q[16];
#pragma unroll
        for (int s = 0; s < 16; ++s) q[s] = ((float*)PFR)[(s * 16 + cc) * 16 + dl];
        __hip_bfloat16* yp = yp0;
        float S2 = 0.f;
#pragma unroll
        for (int k = 0; k < 16; ++k) {
            int i = i0 + k;
            int tt = dir ? 255 - i : i;
            float dt_ = bf2f_s(DTs[tt * DTL + dl]);
            S2 += dt_;
            float Cv[16];
            load16f(&Csm[i * 16], Cv);
            float corr = 0.f;
#pragma unroll
            for (int s = 0; s < 16; ++s) corr += Cv[s] * q[s] * exp2f(A2[s] * S2);
            float ycur = __bfloat162float(*yp);
            *yp = __float2bfloat16(ycur + corr);
            yp += dstep;
        }
    }
}

extern "C" void kernel_launch(void* const* d_in, const int* in_sizes, int n_in,
                              void* d_out, int out_size, void* d_ws, size_t ws_size,
                              hipStream_t stream) {
    const float* x        = (const float*)d_in[0];
    const int*   t        = (const int*)d_in[1];
    const float* patch_w  = (const float*)d_in[2];
    const float* patch_b  = (const float*)d_in[3];
    const float* tw1      = (const float*)d_in[4];
    const float* tb1      = (const float*)d_in[5];
    const float* tw2      = (const float*)d_in[6];
    const float* tb2      = (const float*)d_in[7];
    const float* norm_g   = (const float*)d_in[8];
    const float* norm_b   = (const float*)d_in[9];
    const float* inproj_w = (const float*)d_in[10];
    const float* conv_w   = (const float*)d_in[11];
    const float* conv_b   = (const float*)d_in[12];
    const float* Alog_f   = (const float*)d_in[13];
    const float* D_f      = (const float*)d_in[14];
    const float* xproj_f  = (const float*)d_in[15];
    const float* dtw_f    = (const float*)d_in[16];
    const float* dtb_f    = (const float*)d_in[17];
    const float* Alog_bk  = (const float*)d_in[18];
    const float* D_bk     = (const float*)d_in[19];
    const float* xproj_bk = (const float*)d_in[20];
    const float* dtw_bk   = (const float*)d_in[21];
    const float* dtb_bk   = (const float*)d_in[22];
    const float* outproj_w= (const float*)d_in[23];
    const float* fng      = (const float*)d_in[24];
    const float* fnb      = (const float*)d_in[25];
    const float* fin_w    = (const float*)d_in[26];
    const float* fin_b    = (const float*)d_in[27];
    float* out = (float*)d_out;

    char* base = (char*)d_ws;
    float*          te  = (float*)base;                                   // 16 KB
    float*          h   = (float*)(base + (16UL << 10));                  // 4 MB
    __hip_bfloat16* hn  = (__hip_bfloat16*)(base + (16UL << 10) + (4UL << 20));   // 2 MB
    __hip_bfloat16* xz  = (__hip_bfloat16*)((char*)hn + (2UL << 20));     // 8 MB
    __hip_bfloat16* uu  = (__hip_bfloat16*)((char*)xz + (8UL << 20));     // 4 MB
    float*          pf2 = (float*)((char*)uu + (4UL << 20));              // 2 MB
    __hip_bfloat16* y2  = (__hip_bfloat16*)((char*)pf2 + (2UL << 20));    // 8 MB
    __hip_bfloat16* wbf = (__hip_bfloat16*)((char*)y2 + (8UL << 20));     // 4 MB

    __hip_bfloat16* w_in  = wbf;
    __hip_bfloat16* w_xf  = wbf + 1048576;
    __hip_bfloat16* w_xb  = wbf + 1179648;
    __hip_bfloat16* w_dtf = wbf + 1310720;
    __hip_bfloat16* w_dtb = wbf + 1376256;
    __hip_bfloat16* w_out = wbf + 1441792;

    const int M = BB * LL;                // 4096

    cvt_w<<<1920, 256, 0, stream>>>(inproj_w, xproj_f, xproj_bk, dtw_f, dtw_bk,
                                    outproj_w, wbf);
    patch_embed<<<256, 256, 0, stream>>>(x, patch_w, patch_b, h);
    time_embed<<<BB, 256, 0, stream>>>(t, tw1, tb1, tw2, tb2, te);

    for (int i = 0; i < 4; ++i) {
        ln_kernel<__hip_bfloat16><<<M, 256, 0, stream>>>(
            h, te, norm_g + i * 256, norm_b + i * 256, hn);
        gemm_mfma<128, 128, 2, 2, 4, 4, 0, false, false, 0, true><<<dim3(32, 8), 256, 0, stream>>>(
            hn, w_in + (size_t)i * 262144, nullptr, xz, M, 1024, 256, 256,
            nullptr, nullptr, nullptr, 0);
        conv_silu<<<1024, 256, 0, stream>>>(xz, conv_w + i * 2048, conv_b + i * 512, uu);
        gemm_mfma<32, 64, 2, 2, 1, 2, 0, false, false, 0, false><<<dim3(128, 2), 256, 0, stream>>>(
            uu, w_xf + (size_t)i * 32768, nullptr, pf2, M, 128, 512, 512,
            uu, w_xb + (size_t)i * 32768, nullptr, 64);
        scan_fused<<<1024, 256, 0, stream>>>(uu, pf2,
            w_dtf + (size_t)i * 16384, w_dtb + (size_t)i * 16384,
            dtb_f + i * 512, dtb_bk + i * 512,
            Alog_f + (size_t)i * 8192, Alog_bk + (size_t)i * 8192,
            D_f + i * 512, D_bk + i * 512, y2);
        gemm_mfma<64, 64, 4, 1, 1, 4, 0, true, false, 2, false><<<dim3(64, 4), 256, 0, stream>>>(
            y2, w_out + (size_t)i * 131072, nullptr, h, M, 256, 512, 1024,
            xz, nullptr, nullptr, 0);
    }

    head_fused<<<64, 256, 0, stream>>>(h, fng, fnb, fin_w, fin_b, out);
}